// Round 5
// baseline (233.448 us; speedup 1.0000x reference)
//
#include <hip/hip_runtime.h>
#include <math.h>

#define DIM 1024
#define NPAIRS 512        // DIM/2
#define NLEVELS 9         // l = 1..9 (l=0 segment of params is a no-op)
#define PAR_OFF (2 * DIM) // params floats [2048, 4092) hold levels 1..9
#define NBLOCKS 2048      // 8 blocks/CU * 256 CUs -> full 32-wave residency

// ---------------------------------------------------------------------------
// Kernel 1: collapse the 9 butterfly levels into one complex weight per pair.
// Level l applies z <- (a - i b) * z to z = u[2p] + i u[2p+1], (a,b) shared
// per block of 2^l. Composite weight is row-independent. Runs once, 1 block.
// ---------------------------------------------------------------------------
__global__ void butterfly_weights_kernel(const float* __restrict__ params,
                                         float2* __restrict__ w) {
#pragma unroll
    for (int h = 0; h < 2; ++h) {
        const int p = threadIdx.x + 256 * h;   // pair index, 0..511
        float wr = 1.0f, wi = 0.0f;
        int off = PAR_OFF;
#pragma unroll
        for (int l = 1; l <= NLEVELS; ++l) {
            const int j = p >> (l - 1);
            const float a = params[off + 2 * j];
            const float b = params[off + 2 * j + 1];
            const float nr = wr * a + wi * b;   // (wr + i wi) * (a - i b)
            const float ni = wi * a - wr * b;
            wr = nr; wi = ni;
            off += 2 * (DIM >> l);
        }
        w[p] = make_float2(wr, wi);
    }
}

// ---------------------------------------------------------------------------
// Kernel 2: one wave per row, grid-stride (4 rows/wave), 1-deep prefetch.
//   out = s1*s2 * (W (x) x)   where
//   s1 = artanh(||x||)/||x||,   ||u||^2 = s1^2 * t,
//   t  = sum_p |W_p|^2 * ||z_p||^2   (reduced jointly with ||x||^2),
//   s2 = tanh(||u||)/||u||.
// No LDS, no barriers; weights register-resident per wave.
// ---------------------------------------------------------------------------
__device__ __forceinline__ void process_row(
        const float4 (&v)[4], const float4 (&W)[4],
        float* __restrict__ out, size_t row, int lane) {
    // ---- joint partials: xn2 = sum x^2 ; t = sum |W_p|^2 * ||z_p||^2 ----
    float xn2 = 0.0f, t = 0.0f;
#pragma unroll
    for (int k = 0; k < 4; ++k) {
        const float n0 = v[k].x * v[k].x + v[k].y * v[k].y;
        const float n1 = v[k].z * v[k].z + v[k].w * v[k].w;
        const float a0 = W[k].x * W[k].x + W[k].y * W[k].y;
        const float a1 = W[k].z * W[k].z + W[k].w * W[k].w;
        xn2 += n0 + n1;
        t   += a0 * n0 + a1 * n1;
    }
#pragma unroll
    for (int m = 32; m > 0; m >>= 1) {
        xn2 += __shfl_xor(xn2, m);
        t   += __shfl_xor(t, m);
    }

    // ---- scales: s1 = artanh(r)/r ; s2 = tanh(vn)/vn, vn = s1*sqrt(t) ----
    const float r = sqrtf(xn2);
    const float s1 = (r > 1e-12f)
                         ? (0.5f * __logf((1.0f + r) / (1.0f - r)) / r)
                         : 1.0f;
    float vn = fmaxf(s1 * sqrtf(t), 1e-8f);
    float s2;
    if (vn < 1e-4f) {
        s2 = 1.0f - vn * vn * (1.0f / 3.0f);   // tanh(v)/v series
    } else {
        const float e = __expf(2.0f * vn);
        s2 = (e - 1.0f) / ((e + 1.0f) * vn);
    }
    const float sc = s1 * s2;

    // ---- scaled complex multiply + store ----
    float4* orow = (float4*)(out + row * DIM);
#pragma unroll
    for (int k = 0; k < 4; ++k) {
        float4 o;
        o.x = sc * (W[k].x * v[k].x - W[k].y * v[k].y);
        o.y = sc * (W[k].x * v[k].y + W[k].y * v[k].x);
        o.z = sc * (W[k].z * v[k].z - W[k].w * v[k].w);
        o.w = sc * (W[k].z * v[k].w + W[k].w * v[k].z);
        orow[lane + 64 * k] = o;
    }
}

__global__ __launch_bounds__(256) void hyper_butterfly_main(
        const float* __restrict__ x,
        const float4* __restrict__ w4,   // (wr0,wi0,wr1,wi1) per float4 slot
        float* __restrict__ out,
        int rows) {
    const int lane = threadIdx.x & 63;
    const int wave = threadIdx.x >> 6;
    const int gwave = blockIdx.x * 4 + wave;
    const int nwaves = gridDim.x * 4;

    // weights: load once per wave, register-resident
    float4 W[4];
#pragma unroll
    for (int k = 0; k < 4; ++k) W[k] = w4[lane + 64 * k];

    int row = gwave;
    if (row >= rows) return;

    float4 v[4];
    {
        const float4* xrow = (const float4*)(x + (size_t)row * DIM);
#pragma unroll
        for (int k = 0; k < 4; ++k) v[k] = xrow[lane + 64 * k];
    }

    for (;;) {
        const int next = row + nwaves;
        const bool has_next = next < rows;
        float4 nv[4];
        if (has_next) {
            // prefetch next row BEFORE the current row's dependent chain
            const float4* nxrow = (const float4*)(x + (size_t)next * DIM);
#pragma unroll
            for (int k = 0; k < 4; ++k) nv[k] = nxrow[lane + 64 * k];
        }

        process_row(v, W, out, (size_t)row, lane);

        if (!has_next) break;
        row = next;
#pragma unroll
        for (int k = 0; k < 4; ++k) v[k] = nv[k];
    }
}

extern "C" void kernel_launch(void* const* d_in, const int* in_sizes, int n_in,
                              void* d_out, int out_size, void* d_ws, size_t ws_size,
                              hipStream_t stream) {
    const float* x = (const float*)d_in[0];
    const float* params = (const float*)d_in[1];
    float* out = (float*)d_out;
    float2* w = (float2*)d_ws;  // 512 * 8 B = 4 KB scratch

    const int rows = in_sizes[0] / DIM;
    int nblocks = NBLOCKS;
    const int max_needed = (rows + 3) / 4;   // one wave per row minimum
    if (nblocks > max_needed) nblocks = max_needed;

    butterfly_weights_kernel<<<1, 256, 0, stream>>>(params, w);
    hyper_butterfly_main<<<nblocks, 256, 0, stream>>>(x, (const float4*)w, out, rows);
}